// Round 3
// baseline (600.130 us; speedup 1.0000x reference)
//
#include <hip/hip_runtime.h>

typedef _Float16 half_t;
typedef _Float16 half8 __attribute__((ext_vector_type(8)));
typedef float float4v __attribute__((ext_vector_type(4)));

constexpr int NB = 8, NC = 256, NH = 128, NW = 128;
constexpr int XPAD = 130;  // x stride with zeroed col at slot 0 (x=-1) and 129 (x=128)
constexpr int C1 = 96;     // corr channels padded 81->96

// ---------------------------------------------------------------------------
// Weight prep: k-step-major coalesced layouts.
// WtX1 [27][64][32]: step s: kykx=s/3, ci=(s%3)*32+cq (>=81 -> 0)
// WtX2 [18][64][32]: kykx=s/2, ci=(s&1)*32+cq
// WtX3 [18][16][32]: same K as WtX2, co 0..15 (co>=2 -> 0)
// ---------------------------------------------------------------------------
__global__ void prep_weights_kernel(const float* __restrict__ w1,
                                    const float* __restrict__ w2,
                                    const float* __restrict__ w3,
                                    half_t* __restrict__ WtX1,
                                    half_t* __restrict__ WtX2,
                                    half_t* __restrict__ WtX3) {
  int stride = gridDim.x * blockDim.x;
  int i0 = blockIdx.x * blockDim.x + threadIdx.x;
  for (int i = i0; i < 27 * 64 * 32; i += stride) {
    int s = i >> 11, r = i & 2047, co = r >> 5, cq = r & 31;
    int kykx = s / 3, ci = (s % 3) * 32 + cq;
    int ky = kykx / 3, kx = kykx % 3;
    float v = (ci < 81) ? w1[((co * 81 + ci) * 3 + ky) * 3 + kx] : 0.f;
    WtX1[i] = (half_t)v;
  }
  for (int i = i0; i < 18 * 64 * 32; i += stride) {
    int s = i >> 11, r = i & 2047, co = r >> 5, cq = r & 31;
    int kykx = s >> 1, ci = (s & 1) * 32 + cq;
    int ky = kykx / 3, kx = kykx % 3;
    WtX2[i] = (half_t)w2[((co * 64 + ci) * 3 + ky) * 3 + kx];
  }
  for (int i = i0; i < 18 * 16 * 32; i += stride) {
    int s = i >> 9, r = i & 511, co = r >> 5, cq = r & 31;
    int kykx = s >> 1, ci = (s & 1) * 32 + cq;
    int ky = kykx / 3, kx = kykx % 3;
    float v = (co < 2) ? w3[((co * 64 + ci) * 3 + ky) * 3 + kx] : 0.f;
    WtX3[i] = (half_t)v;
  }
}

// ---------------------------------------------------------------------------
// F2 NCHW fp32 -> NHWC fp16 (L3-resident intermediate).
// Thread = (b, cg, y, x): 8 coalesced dword reads (one per channel), one 16B store.
// ---------------------------------------------------------------------------
__global__ __launch_bounds__(256) void nhwc_kernel(const float* __restrict__ F2,
                                                   half_t* __restrict__ F2n) {
  int v = blockIdx.x * 256 + threadIdx.x;  // 8b * 32cg * 128y * 128x = 2^22
  int x = v & 127, y = (v >> 7) & 127, cg = (v >> 14) & 31, b = v >> 19;
  const float* sp = F2 + (((size_t)(b * NC + cg * 8) * NH + y) * NW + x);
  half8 h;
#pragma unroll
  for (int j = 0; j < 8; ++j) h[j] = (half_t)sp[(size_t)j * NH * NW];
  *(half8*)(F2n + (((size_t)(b * NH + y) * NW + x) * NC + cg * 8)) = h;
}

// ---------------------------------------------------------------------------
// Correlation via MFMA band trick — no LDS, no barriers.
// Block = 1 output row y (8 waves, wave = 16 px). For each 32-ch chunk and dyi:
//   D = mfma(A = F2 window frag (NHWC global), B = F1 frag (NCHW fp32 -> cvt)).
// A lane (q,l15): window1 x1=(x0w-4+l15)&127, window2 x2=(x0w+12+l15)&127, k=q*8+j.
// D[m=q*4+e][n=l15]: px = x0w+l15, dxi = n - m + 8 (two windows cover dxi 0..8).
// Output NHWC96 with x-pad stride 130; pad channels 81..95 and pad cols zeroed here.
// ---------------------------------------------------------------------------
__global__ __launch_bounds__(512) void corr_kernel(const float* __restrict__ F1,
                                                   const half_t* __restrict__ F2n,
                                                   half_t* __restrict__ corr) {
  int bid = blockIdx.x;
  int b = bid & 7, y = bid >> 3;  // batch -> XCD pinning
  int tid = threadIdx.x, wave = tid >> 6, lane = tid & 63;
  int q = lane >> 4, l15 = lane & 15;
  int x0w = wave * 16, xB = x0w + l15;

  float4v acc[9][2];
#pragma unroll
  for (int i = 0; i < 9; ++i)
#pragma unroll
    for (int j = 0; j < 2; ++j)
#pragma unroll
      for (int e = 0; e < 4; ++e) acc[i][j][e] = 0.f;

  const float* F1b = F1 + (size_t)b * NC * NH * NW + (size_t)y * NW + xB;
  const half_t* F2b = F2n + (size_t)b * NH * NW * NC;

  int x1 = (x0w - 4 + l15) & 127;
  int x2 = (x0w + 12 + l15) & 127;

  int rowoff[9];  // row element offsets (scalar: y is block-uniform)
#pragma unroll
  for (int r = 0; r < 9; ++r) rowoff[r] = ((y - 4 + r) & 127) * NW * NC;

  for (int c0 = 0; c0 < NC; c0 += 32) {
    // F1 fragment: 8 coalesced fp32 channel loads, cvt to half8
    half8 bf;
#pragma unroll
    for (int j = 0; j < 8; ++j) bf[j] = (half_t)F1b[(size_t)(c0 + q * 8 + j) * (NH * NW)];
#pragma unroll
    for (int dyi = 0; dyi < 9; ++dyi) {
      const half_t* rp = F2b + rowoff[8 - dyi] + c0 + q * 8;
      half8 a1 = *(const half8*)(rp + x1 * NC);
      half8 a2 = *(const half8*)(rp + x2 * NC);
      acc[dyi][0] = __builtin_amdgcn_mfma_f32_16x16x32_f16(a1, bf, acc[dyi][0], 0, 0, 0);
      acc[dyi][1] = __builtin_amdgcn_mfma_f32_16x16x32_f16(a2, bf, acc[dyi][1], 0, 0, 0);
    }
  }

  half_t* pbase = corr + ((size_t)(b * NH + y) * XPAD + xB + 1) * C1;
  int top1 = l15 + 8 - 4 * q;
  int top2 = l15 - 8 - 4 * q;
#pragma unroll
  for (int dyi = 0; dyi < 9; ++dyi) {
#pragma unroll
    for (int e = 0; e < 4; ++e) {
      int d1 = top1 - e;
      if (d1 >= 0 && d1 <= 8) pbase[dyi * 9 + d1] = (half_t)(acc[dyi][0][e] * 0.0625f);
      int d2 = top2 - e;
      if (d2 >= 0 && d2 <= 8) pbase[dyi * 9 + d2] = (half_t)(acc[dyi][1][e] * 0.0625f);
    }
  }
  if (q == 0) {  // zero pad channels 81..95 for this px
    pbase[81] = (half_t)0.f;
#pragma unroll
    for (int k = 0; k < 7; ++k) *(unsigned int*)((char*)pbase + 164 + 4 * k) = 0u;
  }
  if (tid < 48) {  // zero pad columns (slots 0 and 129): 2 x 192B
    int slot = (tid < 24) ? 0 : 129;
    int o = tid % 24;
    half_t* pp = corr + ((size_t)(b * NH + y) * XPAD + slot) * C1;
    *(unsigned long long*)((char*)pp + o * 8) = 0ull;
  }
}

// ---------------------------------------------------------------------------
// Conv 3x3 (SAME, zero-pad via pad cols + row skip) — no LDS, no barriers.
// Block = 1 row, 4 waves: wave = 64 px (xh) x 32 co (coh). K kykx-major:
// per step uniform (dy,dx), A from WtX (coalesced), B from NHWC activations.
// ---------------------------------------------------------------------------
template <int CIN, int KSPL, bool RELU>
__global__ __launch_bounds__(256) void conv_kernel(const half_t* __restrict__ src,
                                                   const half_t* __restrict__ WtX,
                                                   const float* __restrict__ bias,
                                                   half_t* __restrict__ dst) {
  int bid = blockIdx.x;
  int b = bid & 7, y = bid >> 3;
  int tid = threadIdx.x, w = tid >> 6, lane = tid & 63;
  int q = lane >> 4, l15 = lane & 15;
  int xh = (w & 1) * 64, coh = (w >> 1) * 32;

  float4v acc[2][4];
#pragma unroll
  for (int i = 0; i < 2; ++i)
#pragma unroll
    for (int j = 0; j < 4; ++j)
#pragma unroll
      for (int e = 0; e < 4; ++e) acc[i][j][e] = 0.f;

  const half_t* srcb = src + (size_t)(b * NH) * XPAD * CIN;
  const half_t* wp = WtX + (coh + l15) * 32 + q * 8;
  int xb = xh + l15 + 1;  // padded tcol base

#pragma unroll
  for (int s = 0; s < 9 * KSPL; ++s) {
    int kykx = s / KSPL, ci0 = (s % KSPL) * 32;
    int dy = kykx / 3 - 1, dx = kykx % 3 - 1;
    int ty = y + dy;
    if ((unsigned)ty < (unsigned)NH) {
      half8 a0 = *(const half8*)(wp + s * 2048);
      half8 a1 = *(const half8*)(wp + s * 2048 + 512);
      const half_t* rp = srcb + (size_t)ty * XPAD * CIN + ci0 + q * 8;
#pragma unroll
      for (int nf = 0; nf < 4; ++nf) {
        half8 bf = *(const half8*)(rp + (size_t)(xb + nf * 16 + dx) * CIN);
        acc[0][nf] = __builtin_amdgcn_mfma_f32_16x16x32_f16(a0, bf, acc[0][nf], 0, 0, 0);
        acc[1][nf] = __builtin_amdgcn_mfma_f32_16x16x32_f16(a1, bf, acc[1][nf], 0, 0, 0);
      }
    }
  }

  half_t* drow = dst + (size_t)(b * NH + y) * XPAD * 64;
#pragma unroll
  for (int mf = 0; mf < 2; ++mf) {
    int co = coh + mf * 16 + q * 4;
    float4v bv = *(const float4v*)(bias + co);
#pragma unroll
    for (int nf = 0; nf < 4; ++nf) {
      int x = xh + nf * 16 + l15;
      union { half_t h[4]; unsigned long long u; } pk;
#pragma unroll
      for (int e = 0; e < 4; ++e) {
        float v = acc[mf][nf][e] + bv[e];
        if (RELU) v = v > 0.f ? v : 0.f;
        pk.h[e] = (half_t)v;
      }
      *(unsigned long long*)(drow + (size_t)(x + 1) * 64 + co) = pk.u;
    }
  }
  if (tid < 32) {  // zero pad columns: 2 slots x 128B
    int slot = (tid < 16) ? 0 : 129;
    int o = tid & 15;
    *(unsigned long long*)((char*)(drow + (size_t)slot * 64) + o * 8) = 0ull;
  }
}

// ---------------------------------------------------------------------------
// Conv3 (64 -> 2) as MFMA with 16-co padded weights held in registers.
// Block = 2 rows x 2 x-halves (4 waves). Only q==0 lanes (m=0,1) store.
// ---------------------------------------------------------------------------
__global__ __launch_bounds__(256) void conv3_kernel(const half_t* __restrict__ h2,
                                                    const half_t* __restrict__ WtX3,
                                                    const float* __restrict__ b3,
                                                    float* __restrict__ out) {
  int bid = blockIdx.x;
  int b = bid & 7, y0 = (bid >> 3) * 2;
  int tid = threadIdx.x, w = tid >> 6, lane = tid & 63;
  int q = lane >> 4, l15 = lane & 15;
  int y = y0 + (w >> 1), xh = (w & 1) * 64;

  half8 a[18];
#pragma unroll
  for (int s = 0; s < 18; ++s) a[s] = *(const half8*)(WtX3 + (s * 16 + l15) * 32 + q * 8);

  float4v acc[4];
#pragma unroll
  for (int j = 0; j < 4; ++j)
#pragma unroll
    for (int e = 0; e < 4; ++e) acc[j][e] = 0.f;

  const half_t* hb = h2 + (size_t)(b * NH) * XPAD * 64;
#pragma unroll
  for (int s = 0; s < 18; ++s) {
    int kykx = s >> 1, ci0 = (s & 1) * 32;
    int dy = kykx / 3 - 1, dx = kykx % 3 - 1;
    int ty = y + dy;
    if ((unsigned)ty < (unsigned)NH) {
      const half_t* rp = hb + (size_t)ty * XPAD * 64 + ci0 + q * 8;
#pragma unroll
      for (int nf = 0; nf < 4; ++nf) {
        half8 bf = *(const half8*)(rp + (size_t)(xh + nf * 16 + l15 + 1 + dx) * 64);
        acc[nf] = __builtin_amdgcn_mfma_f32_16x16x32_f16(a[s], bf, acc[nf], 0, 0, 0);
      }
    }
  }

  if (q == 0) {
    float c0v = b3[0], c1v = b3[1];
#pragma unroll
    for (int nf = 0; nf < 4; ++nf) {
      int x = xh + nf * 16 + l15;
      out[((size_t)(b * 2 + 0) * NH + y) * NW + x] = acc[nf][0] + c0v;
      out[((size_t)(b * 2 + 1) * NH + y) * NW + x] = acc[nf][1] + c1v;
    }
  }
}

// ---------------------------------------------------------------------------
extern "C" void kernel_launch(void* const* d_in, const int* in_sizes, int n_in,
                              void* d_out, int out_size, void* d_ws, size_t ws_size,
                              hipStream_t stream) {
  const float* F1 = (const float*)d_in[0];
  const float* F2 = (const float*)d_in[1];
  const float* w1 = (const float*)d_in[2];
  const float* b1 = (const float*)d_in[3];
  const float* w2 = (const float*)d_in[4];
  const float* b2 = (const float*)d_in[5];
  const float* w3 = (const float*)d_in[6];
  const float* b3 = (const float*)d_in[7];
  float* out = (float*)d_out;

  char* ws = (char*)d_ws;
  const size_t f2n_bytes = (size_t)NB * NH * NW * NC * 2;     // 67,108,864
  const size_t corr_bytes = (size_t)NB * NH * XPAD * C1 * 2;  // 25,559,040
  const size_t h_bytes = (size_t)NB * NH * XPAD * 64 * 2;     // 17,039,360

  half_t* F2n = (half_t*)ws;
  half_t* corr = (half_t*)(ws + f2n_bytes);
  half_t* h1 = (half_t*)ws;             // overlaps F2n (dead after corr)
  half_t* h2 = (half_t*)(ws + h_bytes);
  char* wbase = ws + f2n_bytes + corr_bytes;
  half_t* WtX1 = (half_t*)wbase;                       // 110,592 B
  half_t* WtX2 = (half_t*)(wbase + 110592);            // 73,728 B
  half_t* WtX3 = (half_t*)(wbase + 110592 + 73728);    // 18,432 B

  prep_weights_kernel<<<64, 256, 0, stream>>>(w1, w2, w3, WtX1, WtX2, WtX3);
  nhwc_kernel<<<16384, 256, 0, stream>>>(F2, F2n);
  corr_kernel<<<1024, 512, 0, stream>>>(F1, F2n, corr);
  conv_kernel<96, 3, true><<<1024, 256, 0, stream>>>(corr, WtX1, b1, h1);
  conv_kernel<64, 2, true><<<1024, 256, 0, stream>>>(h1, WtX2, b2, h2);
  conv3_kernel<<<512, 256, 0, stream>>>(h2, WtX3, b3, out);
}

// Round 5
// 587.337 us; speedup vs baseline: 1.0218x; 1.0218x over previous
//
#include <hip/hip_runtime.h>

typedef _Float16 half_t;
typedef _Float16 half8 __attribute__((ext_vector_type(8)));
typedef float float4v __attribute__((ext_vector_type(4)));

constexpr int NB = 8, NC = 256, NH = 128, NW = 128;
constexpr int XPAD = 130;  // x stride with zeroed col at slot 0 (x=-1) and 129 (x=128)
constexpr int C1 = 96;     // corr channels padded 81->96

// ---------------------------------------------------------------------------
// Weight prep: k-step-major coalesced layouts.
// WtX1 [27][64][32]: step s: kykx=s/3, ci=(s%3)*32+cq (>=81 -> 0)
// WtX2 [18][64][32]: kykx=s/2, ci=(s&1)*32+cq
// WtX3 [18][16][32]: same K as WtX2, co 0..15 (co>=2 -> 0)
// ---------------------------------------------------------------------------
__global__ void prep_weights_kernel(const float* __restrict__ w1,
                                    const float* __restrict__ w2,
                                    const float* __restrict__ w3,
                                    half_t* __restrict__ WtX1,
                                    half_t* __restrict__ WtX2,
                                    half_t* __restrict__ WtX3) {
  int stride = gridDim.x * blockDim.x;
  int i0 = blockIdx.x * blockDim.x + threadIdx.x;
  for (int i = i0; i < 27 * 64 * 32; i += stride) {
    int s = i >> 11, r = i & 2047, co = r >> 5, cq = r & 31;
    int kykx = s / 3, ci = (s % 3) * 32 + cq;
    int ky = kykx / 3, kx = kykx % 3;
    float v = (ci < 81) ? w1[((co * 81 + ci) * 3 + ky) * 3 + kx] : 0.f;
    WtX1[i] = (half_t)v;
  }
  for (int i = i0; i < 18 * 64 * 32; i += stride) {
    int s = i >> 11, r = i & 2047, co = r >> 5, cq = r & 31;
    int kykx = s >> 1, ci = (s & 1) * 32 + cq;
    int ky = kykx / 3, kx = kykx % 3;
    WtX2[i] = (half_t)w2[((co * 64 + ci) * 3 + ky) * 3 + kx];
  }
  for (int i = i0; i < 18 * 16 * 32; i += stride) {
    int s = i >> 9, r = i & 511, co = r >> 5, cq = r & 31;
    int kykx = s >> 1, ci = (s & 1) * 32 + cq;
    int ky = kykx / 3, kx = kykx % 3;
    float v = (co < 2) ? w3[((co * 64 + ci) * 3 + ky) * 3 + kx] : 0.f;
    WtX3[i] = (half_t)v;
  }
}

// ---------------------------------------------------------------------------
// F2 NCHW fp32 -> NHWC fp16, LDS-bounce transpose for coalesced writes.
// Block = (b, cq, y): 128 px x 64 ch tile. Reads lane-consecutive-x (256B),
// swizzled b128 LDS write/read, 16B-coalesced global writes.
// ---------------------------------------------------------------------------
__global__ __launch_bounds__(256) void nhwc_kernel(const float* __restrict__ F2,
                                                   half_t* __restrict__ F2n) {
  __shared__ __align__(16) half_t T[128 * 64];  // [px][c8*8+j], swizzled, 16 KB
  int bid = blockIdx.x;
  int y = bid & 127, cq = (bid >> 7) & 3, b = bid >> 9;
  int tid = threadIdx.x;

  const float* src = F2 + ((size_t)(b * NC + cq * 64) * NH + y) * NW;
#pragma unroll
  for (int k = 0; k < 4; ++k) {
    int u = tid + k * 256;
    int px = u & 127, c8 = u >> 7;  // c8 in [0,8)
    half8 h;
#pragma unroll
    for (int j = 0; j < 8; ++j) h[j] = (half_t)src[(size_t)(c8 * 8 + j) * (NH * NW) + px];
    int byt = (px * 128 + c8 * 16) ^ ((px & 7) << 4);
    *(half8*)((char*)T + byt) = h;
  }
  __syncthreads();
  half_t* dst = F2n + ((size_t)(b * NH + y) * NW) * NC + cq * 64;
#pragma unroll
  for (int k = 0; k < 4; ++k) {
    int u = tid + k * 256;
    int c8 = u & 7, px = u >> 3;
    int byt = (px * 128 + c8 * 16) ^ ((px & 7) << 4);
    *(half8*)(dst + (size_t)px * NC + c8 * 8) = *(const half8*)((const char*)T + byt);
  }
}

// ---------------------------------------------------------------------------
// Correlation via MFMA band trick — r-outer restructure (latency fix).
// Block = 1 output row y (8 waves, wave = 16 px). F1 frags (8 chunks) held in
// registers; per F2 row r (dyi = 8-r): acc is only 2 float4 -> big VGPR
// headroom for batched A-frag loads.
// Windows at -4 (x1) and +4 (x2): D[m=q*4+e][n=l15], dxi1 = n-m+8, dxi2 = n-m.
// Disjoint stores: w1 iff q<2 && dxi1 in [0,8]; w2 iff dxi2 in [0,8].
// ---------------------------------------------------------------------------
__global__ __launch_bounds__(512, 4) void corr_kernel(const float* __restrict__ F1,
                                                      const half_t* __restrict__ F2n,
                                                      half_t* __restrict__ corr) {
  int bid = blockIdx.x;
  int b = bid & 7, y = bid >> 3;  // batch -> XCD pinning
  int tid = threadIdx.x, wave = tid >> 6, lane = tid & 63;
  int q = lane >> 4, l15 = lane & 15;
  int x0w = wave * 16, xB = x0w + l15;

  // F1 fragments for all 8 chunks: 32 VGPRs, loaded once (coalesced per line)
  const float* F1p = F1 + (size_t)b * NC * NH * NW + (size_t)y * NW + xB;
  half8 bfr[8];
#pragma unroll
  for (int c = 0; c < 8; ++c) {
    half8 t;
#pragma unroll
    for (int j = 0; j < 8; ++j) t[j] = (half_t)F1p[(size_t)(c * 32 + q * 8 + j) * (NH * NW)];
    bfr[c] = t;
  }

  const half_t* F2b = F2n + (size_t)b * NH * NW * NC + q * 8;
  int x1 = (x0w - 4 + l15) & 127;
  int x2 = (x0w + 4 + l15) & 127;
  const half_t* p1 = F2b + (size_t)x1 * NC;
  const half_t* p2 = F2b + (size_t)x2 * NC;

  half_t* pb0 = corr + ((size_t)(b * NH + y) * XPAD + xB + 1) * C1;
  int dbase = l15 - 4 * q;

#pragma unroll
  for (int r = 0; r < 9; ++r) {
    size_t ro = (size_t)((y - 4 + r) & 127) * (NW * NC);
    float4v a0, a1;
#pragma unroll
    for (int e = 0; e < 4; ++e) { a0[e] = 0.f; a1[e] = 0.f; }
#pragma unroll
    for (int c = 0; c < 8; ++c) {
      half8 f1 = *(const half8*)(p1 + ro + c * 32);
      half8 f2 = *(const half8*)(p2 + ro + c * 32);
      a0 = __builtin_amdgcn_mfma_f32_16x16x32_f16(f1, bfr[c], a0, 0, 0, 0);
      a1 = __builtin_amdgcn_mfma_f32_16x16x32_f16(f2, bfr[c], a1, 0, 0, 0);
    }
    // store band for dyi = 8 - r
    half_t* pb = pb0 + (8 - r) * 9;
#pragma unroll
    for (int e = 0; e < 4; ++e) {
      int d1 = dbase - e + 8;
      if (q < 2 && (unsigned)d1 <= 8u) pb[d1] = (half_t)(a0[e] * 0.0625f);
      int d2 = dbase - e;
      if ((unsigned)d2 <= 8u) pb[d2] = (half_t)(a1[e] * 0.0625f);
    }
  }

  if (q == 0) {  // zero pad channels 81..95 for this px
    pb0[81] = (half_t)0.f;
#pragma unroll
    for (int k = 0; k < 7; ++k) *(unsigned int*)((char*)pb0 + 164 + 4 * k) = 0u;
  }
  if (tid < 48) {  // zero pad columns (slots 0 and 129): 2 x 192B
    int slot = (tid < 24) ? 0 : 129;
    int o = tid % 24;
    half_t* pp = corr + ((size_t)(b * NH + y) * XPAD + slot) * C1;
    *(unsigned long long*)((char*)pp + o * 8) = 0ull;
  }
}

// ---------------------------------------------------------------------------
// Conv 3x3 (SAME, zero-pad via pad cols + row skip) — no LDS, no barriers.
// Block = 1 row, 4 waves: wave = 64 px (xh) x 32 co (coh). K kykx-major:
// per step uniform (dy,dx), A from WtX (coalesced), B from NHWC activations.
// ---------------------------------------------------------------------------
template <int CIN, int KSPL, bool RELU>
__global__ __launch_bounds__(256) void conv_kernel(const half_t* __restrict__ src,
                                                   const half_t* __restrict__ WtX,
                                                   const float* __restrict__ bias,
                                                   half_t* __restrict__ dst) {
  int bid = blockIdx.x;
  int b = bid & 7, y = bid >> 3;
  int tid = threadIdx.x, w = tid >> 6, lane = tid & 63;
  int q = lane >> 4, l15 = lane & 15;
  int xh = (w & 1) * 64, coh = (w >> 1) * 32;

  float4v acc[2][4];
#pragma unroll
  for (int i = 0; i < 2; ++i)
#pragma unroll
    for (int j = 0; j < 4; ++j)
#pragma unroll
      for (int e = 0; e < 4; ++e) acc[i][j][e] = 0.f;

  const half_t* srcb = src + (size_t)(b * NH) * XPAD * CIN;
  const half_t* wp = WtX + (coh + l15) * 32 + q * 8;
  int xb = xh + l15 + 1;  // padded tcol base

#pragma unroll
  for (int s = 0; s < 9 * KSPL; ++s) {
    int kykx = s / KSPL, ci0 = (s % KSPL) * 32;
    int dy = kykx / 3 - 1, dx = kykx % 3 - 1;
    int ty = y + dy;
    if ((unsigned)ty < (unsigned)NH) {
      half8 a0 = *(const half8*)(wp + s * 2048);
      half8 a1 = *(const half8*)(wp + s * 2048 + 512);
      const half_t* rp = srcb + (size_t)ty * XPAD * CIN + ci0 + q * 8;
#pragma unroll
      for (int nf = 0; nf < 4; ++nf) {
        half8 bf = *(const half8*)(rp + (size_t)(xb + nf * 16 + dx) * CIN);
        acc[0][nf] = __builtin_amdgcn_mfma_f32_16x16x32_f16(a0, bf, acc[0][nf], 0, 0, 0);
        acc[1][nf] = __builtin_amdgcn_mfma_f32_16x16x32_f16(a1, bf, acc[1][nf], 0, 0, 0);
      }
    }
  }

  half_t* drow = dst + (size_t)(b * NH + y) * XPAD * 64;
#pragma unroll
  for (int mf = 0; mf < 2; ++mf) {
    int co = coh + mf * 16 + q * 4;
    float4v bv = *(const float4v*)(bias + co);
#pragma unroll
    for (int nf = 0; nf < 4; ++nf) {
      int x = xh + nf * 16 + l15;
      union { half_t h[4]; unsigned long long u; } pk;
#pragma unroll
      for (int e = 0; e < 4; ++e) {
        float v = acc[mf][nf][e] + bv[e];
        if (RELU) v = v > 0.f ? v : 0.f;
        pk.h[e] = (half_t)v;
      }
      *(unsigned long long*)(drow + (size_t)(x + 1) * 64 + co) = pk.u;
    }
  }
  if (tid < 32) {  // zero pad columns: 2 slots x 128B
    int slot = (tid < 16) ? 0 : 129;
    int o = tid & 15;
    *(unsigned long long*)((char*)(drow + (size_t)slot * 64) + o * 8) = 0ull;
  }
}

// ---------------------------------------------------------------------------
// Conv3 (64 -> 2) as MFMA with 16-co padded weights held in registers.
// Block = 2 rows x 2 x-halves (4 waves). Only q==0 lanes (m=0,1) store.
// ---------------------------------------------------------------------------
__global__ __launch_bounds__(256) void conv3_kernel(const half_t* __restrict__ h2,
                                                    const half_t* __restrict__ WtX3,
                                                    const float* __restrict__ b3,
                                                    float* __restrict__ out) {
  int bid = blockIdx.x;
  int b = bid & 7, y0 = (bid >> 3) * 2;
  int tid = threadIdx.x, w = tid >> 6, lane = tid & 63;
  int q = lane >> 4, l15 = lane & 15;
  int y = y0 + (w >> 1), xh = (w & 1) * 64;

  half8 a[18];
#pragma unroll
  for (int s = 0; s < 18; ++s) a[s] = *(const half8*)(WtX3 + (s * 16 + l15) * 32 + q * 8);

  float4v acc[4];
#pragma unroll
  for (int j = 0; j < 4; ++j)
#pragma unroll
    for (int e = 0; e < 4; ++e) acc[j][e] = 0.f;

  const half_t* hb = h2 + (size_t)(b * NH) * XPAD * 64;
#pragma unroll
  for (int s = 0; s < 18; ++s) {
    int kykx = s >> 1, ci0 = (s & 1) * 32;
    int dy = kykx / 3 - 1, dx = kykx % 3 - 1;
    int ty = y + dy;
    if ((unsigned)ty < (unsigned)NH) {
      const half_t* rp = hb + (size_t)ty * XPAD * 64 + ci0 + q * 8;
#pragma unroll
      for (int nf = 0; nf < 4; ++nf) {
        half8 bf = *(const half8*)(rp + (size_t)(xh + nf * 16 + l15 + 1 + dx) * 64);
        acc[nf] = __builtin_amdgcn_mfma_f32_16x16x32_f16(a[s], bf, acc[nf], 0, 0, 0);
      }
    }
  }

  if (q == 0) {
    float c0v = b3[0], c1v = b3[1];
#pragma unroll
    for (int nf = 0; nf < 4; ++nf) {
      int x = xh + nf * 16 + l15;
      out[((size_t)(b * 2 + 0) * NH + y) * NW + x] = acc[nf][0] + c0v;
      out[((size_t)(b * 2 + 1) * NH + y) * NW + x] = acc[nf][1] + c1v;
    }
  }
}

// ---------------------------------------------------------------------------
extern "C" void kernel_launch(void* const* d_in, const int* in_sizes, int n_in,
                              void* d_out, int out_size, void* d_ws, size_t ws_size,
                              hipStream_t stream) {
  const float* F1 = (const float*)d_in[0];
  const float* F2 = (const float*)d_in[1];
  const float* w1 = (const float*)d_in[2];
  const float* b1 = (const float*)d_in[3];
  const float* w2 = (const float*)d_in[4];
  const float* b2 = (const float*)d_in[5];
  const float* w3 = (const float*)d_in[6];
  const float* b3 = (const float*)d_in[7];
  float* out = (float*)d_out;

  char* ws = (char*)d_ws;
  const size_t f2n_bytes = (size_t)NB * NH * NW * NC * 2;     // 67,108,864
  const size_t corr_bytes = (size_t)NB * NH * XPAD * C1 * 2;  // 25,559,040
  const size_t h_bytes = (size_t)NB * NH * XPAD * 64 * 2;     // 17,039,360

  half_t* F2n = (half_t*)ws;
  half_t* corr = (half_t*)(ws + f2n_bytes);
  half_t* h1 = (half_t*)ws;  // overlaps F2n (dead after corr)
  half_t* h2 = (half_t*)(ws + h_bytes);
  char* wbase = ws + f2n_bytes + corr_bytes;
  half_t* WtX1 = (half_t*)wbase;                     // 110,592 B
  half_t* WtX2 = (half_t*)(wbase + 110592);          // 73,728 B
  half_t* WtX3 = (half_t*)(wbase + 110592 + 73728);  // 18,432 B

  prep_weights_kernel<<<64, 256, 0, stream>>>(w1, w2, w3, WtX1, WtX2, WtX3);
  nhwc_kernel<<<4096, 256, 0, stream>>>(F2, F2n);
  corr_kernel<<<1024, 512, 0, stream>>>(F1, F2n, corr);
  conv_kernel<96, 3, true><<<1024, 256, 0, stream>>>(corr, WtX1, b1, h1);
  conv_kernel<64, 2, true><<<1024, 256, 0, stream>>>(h1, WtX2, b2, h2);
  conv3_kernel<<<512, 256, 0, stream>>>(h2, WtX3, b3, out);
}